// Round 1
// baseline (254.307 us; speedup 1.0000x reference)
//
#include <hip/hip_runtime.h>
#include <cstdint>

// MultiHeadAttention: B=2 S=2048 D=768 H=12 dk=64, fp32 in/out, bf16 MFMA inside.
//
//   convert_all : q,k,v,w_q,w_k,w_v,w_o fp32 -> bf16              (ws)
//   qkv         : m97-style GEMM: global_load_lds width-16 DMA staging,
//                 single-buffered LDS, 2 barriers/iter, 128x128 tile.
//   attn        : ctx[tok][768] = flash attention (no-max softmax) (bf16, ws)
//                 R1: V read DIRECT from global (L1/L2-resident) instead of
//                 LDS-staged -- attn was LDS-issue-bound (~26 LDS ops/wave/tile
//                 at ~85 B/cyc = ~80% LDS pipe busy while MfmaUtil=20%).
//                 V moves to the idle VMEM pipe; vbuf deleted. + s_setprio(T5).
//   o           : 64x128-tile DMA GEMM -> fp32 d_out

#define S_LEN 2048
#define NHEAD 12
#define DMODEL 768

typedef short s16x8 __attribute__((ext_vector_type(8)));
typedef float f32x4 __attribute__((ext_vector_type(4)));

#define MFMA16(a, b, c) __builtin_amdgcn_mfma_f32_16x16x32_bf16((a), (b), (c), 0, 0, 0)

__device__ __forceinline__ void lds_dma16(void* lds, const void* g) {
  __builtin_amdgcn_global_load_lds(
      (const __attribute__((address_space(1))) unsigned int*)g,
      (__attribute__((address_space(3))) unsigned int*)lds, 16, 0, 0);
}

__device__ __forceinline__ unsigned int pk_bf16(float a, float b) {
  unsigned int ua = __float_as_uint(a), ub = __float_as_uint(b);
  ua = (ua + 0x7FFFu + ((ua >> 16) & 1u)) >> 16;   // RNE
  ub = (ub + 0x7FFFu + ((ub >> 16) & 1u)) >> 16;
  return ua | (ub << 16);
}
__device__ __forceinline__ short bf16r(float a) {
  unsigned int ua = __float_as_uint(a);
  return (short)((ua + 0x7FFFu + ((ua >> 16) & 1u)) >> 16);
}
// pack hi16(b)<<16 | hi16(a) in ONE v_perm_b32 (trunc; bias cancelled via l)
__device__ __forceinline__ unsigned int pk_trunc(float a, float b) {
  return __builtin_amdgcn_perm(__float_as_uint(b), __float_as_uint(a), 0x07060302u);
}
__device__ __forceinline__ float bf16_floor(float a) {
  return __uint_as_float(__float_as_uint(a) & 0xFFFF0000u);
}

// ---------------------------------------------------------------------------
// All fp32 -> bf16 conversions in ONE launch. 11520 blocks x 256 thr x
// float4/thr: blocks [0,9216) = q,k,v (3072 each); [9216,11520) = 4 weights
// (576 each).
// ---------------------------------------------------------------------------
__global__ __launch_bounds__(256)
void convert_all(const float* __restrict__ q, const float* __restrict__ k,
                 const float* __restrict__ v,
                 const float* __restrict__ w0, const float* __restrict__ w1,
                 const float* __restrict__ w2, const float* __restrict__ w3,
                 short* __restrict__ qb, short* __restrict__ kb,
                 short* __restrict__ vb,
                 short* __restrict__ o0, short* __restrict__ o1,
                 short* __restrict__ o2, short* __restrict__ o3) {
  int b = blockIdx.x;
  const float* src;
  short* dst;
  if (b < 9216) {
    const int s = b / 3072;
    src = (s == 0) ? q : (s == 1) ? k : v;
    dst = (s == 0) ? qb : (s == 1) ? kb : vb;
    b -= s * 3072;
  } else {
    b -= 9216;
    const int s = b / 576;
    src = (s == 0) ? w0 : (s == 1) ? w1 : (s == 2) ? w2 : w3;
    dst = (s == 0) ? o0 : (s == 1) ? o1 : (s == 2) ? o2 : o3;
    b -= s * 576;
  }
  const long i = ((long)b * 256 + threadIdx.x) * 4;
  float4 f = *(const float4*)(src + i);
  uint2 u;
  u.x = pk_bf16(f.x, f.y);
  u.y = pk_bf16(f.z, f.w);
  *(uint2*)(dst + i) = u;
}

// ---------------------------------------------------------------------------
// Fused QKV projection, m97-style. 576 blocks, XCD-swizzled.
// Tile 128x128, BK=32, 4 waves each 64x64 (acc[4][4]).
// Staging: global_load_lds x4 per wave (A 2, B 2), LDS rows of 32 shorts.
// ---------------------------------------------------------------------------
__global__ __launch_bounds__(256)
void qkv_kernel(const short* __restrict__ qb, const short* __restrict__ kb,
                const short* __restrict__ vb,
                const short* __restrict__ wq, const short* __restrict__ wk,
                const short* __restrict__ wv,
                const float* __restrict__ bq, const float* __restrict__ bk,
                const float* __restrict__ bv,
                short* __restrict__ qh, short* __restrict__ kh,
                short* __restrict__ vt) {
  constexpr int K = 768;
  __shared__ short Abuf[128 * 32];   // [row][k], 64B rows
  __shared__ short Bbuf[128 * 32];

  const int L   = blockIdx.x;        // 0..575
  const int xcd = L & 7;
  const int i   = L >> 3;            // 0..71
  const int nt  = i % 6;
  const int pl  = xcd * 12 + i / 6;  // 0..95 (m,z) pair
  const int z   = pl >> 5;           // 32 m-tiles per z
  const int mt  = pl & 31;
  const int m0  = mt * 128;          // token
  const int n0  = nt * 128;          // feature

  const short* A = (z == 0) ? qb : (z == 1) ? kb : vb;
  const short* B = (z == 0) ? wq : (z == 1) ? wk : wv;
  const float* bias = (z == 0) ? bq : (z == 1) ? bk : bv;

  const int tid  = threadIdx.x;
  const int lane = tid & 63;
  const int w    = tid >> 6;
  const int g    = lane >> 4;
  const int c    = lane & 15;
  const int wm   = (w & 1) * 64;
  const int wn   = (w >> 1) * 64;

  // DMA addressing: wave w covers rows [w*32, w*32+32), 2 insts x 16 rows.
  // lane l -> row +l/4, col (l&3)*8; LDS linear dest = base + l*16B.
  const int drow = w * 32 + (lane >> 2);
  const int dcol = (lane & 3) * 8;
  const short* Ag = A + (long)(m0 + drow) * K + dcol;
  const short* Bg = B + (long)(n0 + drow) * K + dcol;
  short* Al0 = &Abuf[w * 1024];
  short* Al1 = &Abuf[w * 1024 + 512];
  short* Bl0 = &Bbuf[w * 1024];
  short* Bl1 = &Bbuf[w * 1024 + 512];

  f32x4 acc[4][4];
#pragma unroll
  for (int a = 0; a < 4; ++a)
#pragma unroll
    for (int b2 = 0; b2 < 4; ++b2) acc[a][b2] = (f32x4){0.f, 0.f, 0.f, 0.f};

  for (int kt = 0; kt < K; kt += 32) {
    lds_dma16(Al0, Ag + kt);
    lds_dma16(Al1, Ag + (long)16 * K + kt);
    lds_dma16(Bl0, Bg + kt);
    lds_dma16(Bl1, Bg + (long)16 * K + kt);
    __syncthreads();   // vmcnt(0) drain: DMA landed

    s16x8 af[4], bf[4];
#pragma unroll
    for (int mb = 0; mb < 4; ++mb)
      af[mb] = *(const s16x8*)&Abuf[(wm + mb * 16 + c) * 32 + g * 8];
#pragma unroll
    for (int nb = 0; nb < 4; ++nb)
      bf[nb] = *(const s16x8*)&Bbuf[(wn + nb * 16 + c) * 32 + g * 8];
#pragma unroll
    for (int mb = 0; mb < 4; ++mb)
#pragma unroll
      for (int nb = 0; nb < 4; ++nb)
        acc[mb][nb] = MFMA16(af[mb], bf[nb], acc[mb][nb]);
    __syncthreads();   // safe to overwrite LDS
  }

  if (z < 2) {
    short* outp = z ? kh : qh;
    const float scale = z ? 1.0f : 0.18033688011112042f;  // log2e/8
#pragma unroll
    for (int mb = 0; mb < 4; ++mb) {
#pragma unroll
      for (int nb = 0; nb < 4; ++nb) {
        const int n = n0 + wn + nb * 16 + c;
        const float bvv = bias[n];
        const int hh = n >> 6, d = n & 63;
#pragma unroll
        for (int r = 0; r < 4; ++r) {
          const int m = m0 + wm + mb * 16 + g * 4 + r;
          const int b2 = m >> 11, s = m & 2047;
          const float val = (acc[mb][nb][r] + bvv) * scale;
          outp[(((long)(b2 * NHEAD + hh) * S_LEN + s) << 6) + d] = bf16r(val);
        }
      }
    }
  } else {  // V: transposed write Vt[b][h][d][t], 4 consecutive t per lane
#pragma unroll
    for (int mb = 0; mb < 4; ++mb) {
#pragma unroll
      for (int nb = 0; nb < 4; ++nb) {
        const int n = n0 + wn + nb * 16 + c;   // feature
        const float bvv = bias[n];
        const int hh = n >> 6, d = n & 63;
        const int m_base = m0 + wm + mb * 16 + g * 4;   // token base
        const int b2 = m_base >> 11, t = m_base & 2047;
        uint2 ov;
        ov.x = pk_bf16(acc[mb][nb][0] + bvv, acc[mb][nb][1] + bvv);
        ov.y = pk_bf16(acc[mb][nb][2] + bvv, acc[mb][nb][3] + bvv);
        *(uint2*)(vt + ((long)(b2 * NHEAD + hh) * 64 + d) * S_LEN + t) = ov;
      }
    }
  }
}

// ---------------------------------------------------------------------------
// Output projection, m97-style 64x128 tile. 384 blocks, XCD-swizzled.
// A = ctx (bf16), B = w_o (bf16), out fp32. Wave tile 32x64, acc[2][4].
// ---------------------------------------------------------------------------
__global__ __launch_bounds__(256)
void o_kernel(const short* __restrict__ ctx, const short* __restrict__ wo,
              const float* __restrict__ bo, float* __restrict__ out) {
  constexpr int K = 768;
  __shared__ short Abuf[64 * 32];
  __shared__ short Bbuf[128 * 32];

  const int L   = blockIdx.x;        // 0..383
  const int xcd = L & 7;
  const int i   = L >> 3;            // 0..47
  const int nt  = i % 6;
  const int mt  = xcd * 8 + i / 6;   // 0..63
  const int m0  = mt * 64;
  const int n0  = nt * 128;

  const int tid  = threadIdx.x;
  const int lane = tid & 63;
  const int w    = tid >> 6;
  const int g    = lane >> 4;
  const int c    = lane & 15;
  const int wm   = (w & 1) * 32;
  const int wn   = (w >> 1) * 64;

  // A: wave w covers rows [w*16, w*16+16), 1 inst. B: rows [w*32,+32), 2.
  const int arow = w * 16 + (lane >> 2);
  const int brow = w * 32 + (lane >> 2);
  const int dcol = (lane & 3) * 8;
  const short* Ag = ctx + (long)(m0 + arow) * K + dcol;
  const short* Bg = wo + (long)(n0 + brow) * K + dcol;
  short* Al = &Abuf[w * 512];
  short* Bl0 = &Bbuf[w * 1024];
  short* Bl1 = &Bbuf[w * 1024 + 512];

  f32x4 acc[2][4];
#pragma unroll
  for (int a = 0; a < 2; ++a)
#pragma unroll
    for (int b2 = 0; b2 < 4; ++b2) acc[a][b2] = (f32x4){0.f, 0.f, 0.f, 0.f};

  for (int kt = 0; kt < K; kt += 32) {
    lds_dma16(Al, Ag + kt);
    lds_dma16(Bl0, Bg + kt);
    lds_dma16(Bl1, Bg + (long)16 * K + kt);
    __syncthreads();

    s16x8 af[2], bf[4];
#pragma unroll
    for (int mb = 0; mb < 2; ++mb)
      af[mb] = *(const s16x8*)&Abuf[(wm + mb * 16 + c) * 32 + g * 8];
#pragma unroll
    for (int nb = 0; nb < 4; ++nb)
      bf[nb] = *(const s16x8*)&Bbuf[(wn + nb * 16 + c) * 32 + g * 8];
#pragma unroll
    for (int mb = 0; mb < 2; ++mb)
#pragma unroll
      for (int nb = 0; nb < 4; ++nb)
        acc[mb][nb] = MFMA16(af[mb], bf[nb], acc[mb][nb]);
    __syncthreads();
  }

#pragma unroll
  for (int mb = 0; mb < 2; ++mb) {
#pragma unroll
    for (int nb = 0; nb < 4; ++nb) {
      const int n = n0 + wn + nb * 16 + c;
      const float bvv = bo[n];
#pragma unroll
      for (int r = 0; r < 4; ++r) {
        const int m = m0 + wm + mb * 16 + g * 4 + r;
        out[(long)m * DMODEL + n] = acc[mb][nb][r] + bvv;
      }
    }
  }
}

// ---------------------------------------------------------------------------
// Flash attention, no-max softmax.
// R1: K LDS-staged (double-buffered, XOR-swizzled) as before; V fragments
// loaded DIRECTLY from global (Vt is t-major, so V[d][t0+g*8] IS the MFMA
// A-fragment). vbuf deleted (LDS 40 KB -> 24 KB); ~10 of 26 LDS ops per
// wave-tile move to the idle VMEM pipe (L1-hit: 4 waves share each line).
// s_setprio(1) around the pure-reg PV MFMA cluster (T5).
// ---------------------------------------------------------------------------
__global__ __launch_bounds__(256)
void attn_kernel(const short* __restrict__ Qh, const short* __restrict__ Kh,
                 const short* __restrict__ Vt, short* __restrict__ Ctx) {
  __shared__ short kbuf[2][64 * 64];      // swizzled [t][d]
  __shared__ short pbuf[4][16 * 64];      // per-wave [s][t], XOR-swizzled

  const int tid  = threadIdx.x;
  const int lane = tid & 63;
  const int w    = tid >> 6;
  const int g    = lane >> 4;
  const int c    = lane & 15;
  const int bh   = blockIdx.y;            // 0..23
  const int qs0  = blockIdx.x * 64;
  const long base = (long)bh * S_LEN * 64;
  const short* Qb = Qh + base;
  const short* Kb = Kh + base;
  const short* Vb = Vt + base;

  const long qrow = (long)(qs0 + w * 16 + c) * 64;
  const s16x8 qf0 = *(const s16x8*)(Qb + qrow + g * 8);
  const s16x8 qf1 = *(const s16x8*)(Qb + qrow + 32 + g * 8);

  f32x4 co[4];
#pragma unroll
  for (int i = 0; i < 4; ++i) co[i] = (f32x4){0.f, 0.f, 0.f, 0.f};
  float l_lane = 0.f;

  const int srow = tid >> 2;           // 0..63  (t-row for K staging)
  const int sq   = tid & 3;
  const int sw   = srow & 7;
  const int sg0  = ((2 * sq)     ^ sw) * 8;
  const int sg1  = ((2 * sq + 1) ^ sw) * 8;
  const int cw   = c & 7;
  const int rg0  = ((g)     ^ cw) * 8;
  const int rg1  = ((4 + g) ^ cw) * 8;

  const short* kg = Kb + (long)srow * 64 + sq * 16;     // + row*64
  // V direct-load base: lane (g,c) reads V[d = db*16+c][t0 + g*8 (+32)]
  const short* vbase = Vb + (long)c * S_LEN + g * 8;

  uint4 rkA0, rkA1;
  uint4 rkB0, rkB1;
  auto fetchA = [&](long t0) {    // t0 = starting row (tile*64)
    rkA0 = *(const uint4*)(kg + t0 * 64);
    rkA1 = *(const uint4*)(kg + t0 * 64 + 8);
  };
  auto fetchB = [&](long t0) {
    rkB0 = *(const uint4*)(kg + t0 * 64);
    rkB1 = *(const uint4*)(kg + t0 * 64 + 8);
  };
  auto storeA = [&](short* kb2) {
    *(uint4*)&kb2[srow * 64 + sg0] = rkA0;
    *(uint4*)&kb2[srow * 64 + sg1] = rkA1;
  };
  auto storeB = [&](short* kb2) {
    *(uint4*)&kb2[srow * 64 + sg0] = rkB0;
    *(uint4*)&kb2[srow * 64 + sg1] = rkB1;
  };

  const int pr0 = c * 64 + ((g ^ cw) * 8);
  const int pr1 = c * 64 + (((4 + g) ^ cw) * 8);

  auto step = [&](const short* kb2, long t0) {
    // V fragments direct from global (L1/L2-resident); issued first so the
    // ~200cy L2 latency hides under QK^T + softmax.
    s16x8 vf0[4], vf1[4];
#pragma unroll
    for (int db = 0; db < 4; ++db) {
      const short* vp = vbase + (long)db * 16 * S_LEN + t0;
      vf0[db] = *(const s16x8*)vp;
      vf1[db] = *(const s16x8*)(vp + 32);
    }
    f32x4 st[4];
#pragma unroll
    for (int mb = 0; mb < 4; ++mb) {
      const s16x8 k0 = *(const s16x8*)&kb2[(mb * 16 + c) * 64 + rg0];
      const s16x8 k1 = *(const s16x8*)&kb2[(mb * 16 + c) * 64 + rg1];
      f32x4 z = (f32x4){0.f, 0.f, 0.f, 0.f};
      z = MFMA16(k0, qf0, z);
      z = MFMA16(k1, qf1, z);
      st[mb] = z;
    }
#pragma unroll
    for (int mb = 0; mb < 4; ++mb) {
      float p0 = __builtin_amdgcn_exp2f(st[mb][0]);
      float p1 = __builtin_amdgcn_exp2f(st[mb][1]);
      float p2 = __builtin_amdgcn_exp2f(st[mb][2]);
      float p3 = __builtin_amdgcn_exp2f(st[mb][3]);
      l_lane += bf16_floor(p0) + bf16_floor(p1) + bf16_floor(p2) + bf16_floor(p3);
      uint2 pw;
      pw.x = pk_trunc(p0, p1);
      pw.y = pk_trunc(p2, p3);
      const int pg = ((2 * mb + (g >> 1)) ^ cw) * 8 + (g & 1) * 4;
      *(uint2*)&pbuf[w][c * 64 + pg] = pw;
    }
    const s16x8 pb0 = *(const s16x8*)&pbuf[w][pr0];
    const s16x8 pb1 = *(const s16x8*)&pbuf[w][pr1];
    __builtin_amdgcn_s_setprio(1);
#pragma unroll
    for (int db = 0; db < 4; ++db) {
      co[db] = MFMA16(vf0[db], pb0, co[db]);
      co[db] = MFMA16(vf1[db], pb1, co[db]);
    }
    __builtin_amdgcn_s_setprio(0);
  };

  constexpr int NT = S_LEN / 64;   // 32 tiles
  fetchA(0);
  fetchB(64);
  storeA(kbuf[0]);
  for (int j = 0; j < NT / 2; ++j) {
    __syncthreads();                                        // buf0 (tile 2j)
    fetchA((2 * j + 2 < NT) ? (long)(2 * j + 2) * 64 : 0);  // tile 2j+2 -> A
    step(kbuf[0], (long)(2 * j) * 64);
    storeB(kbuf[1]);                                        // tile 2j+1 -> buf1
    __syncthreads();                                        // buf1 visible
    fetchB((2 * j + 3 < NT) ? (long)(2 * j + 3) * 64 : 0);  // tile 2j+3 -> B
    step(kbuf[1], (long)(2 * j + 1) * 64);
    storeA(kbuf[0]);                                        // tile 2j+2 -> buf0
  }

  float rs = l_lane;
  rs += __shfl_xor(rs, 16);
  rs += __shfl_xor(rs, 32);
  const float invl = 1.f / rs;

  const int hh = bh % NHEAD;
  const long tok = (long)(bh / NHEAD) * S_LEN + qs0 + w * 16 + c;
#pragma unroll
  for (int db = 0; db < 4; ++db) {
    uint2 ov;
    ov.x = pk_bf16(co[db][0] * invl, co[db][1] * invl);
    ov.y = pk_bf16(co[db][2] * invl, co[db][3] * invl);
    *(uint2*)(Ctx + tok * DMODEL + hh * 64 + db * 16 + g * 4) = ov;
  }
}

// ---------------------------------------------------------------------------
extern "C" void kernel_launch(void* const* d_in, const int* in_sizes, int n_in,
                              void* d_out, int out_size, void* d_ws, size_t ws_size,
                              hipStream_t stream) {
  const float* q   = (const float*)d_in[0];
  const float* k   = (const float*)d_in[1];
  const float* v   = (const float*)d_in[2];
  const float* w_q = (const float*)d_in[3];
  const float* b_q = (const float*)d_in[4];
  const float* w_k = (const float*)d_in[5];
  const float* b_k = (const float*)d_in[6];
  const float* w_v = (const float*)d_in[7];
  const float* b_v = (const float*)d_in[8];
  const float* w_o = (const float*)d_in[9];
  const float* b_o = (const float*)d_in[10];
  float* out = (float*)d_out;

  const long NELEM = (long)2 * NHEAD * S_LEN * 64;  // 3,145,728
  const long WELEM = (long)DMODEL * DMODEL;         // 589,824
  short* qh  = (short*)d_ws;
  short* kh  = qh + NELEM;
  short* vt  = kh + NELEM;
  short* wqb = vt + NELEM;
  short* wkb = wqb + WELEM;
  short* wvb = wkb + WELEM;
  short* wob = wvb + WELEM;
  short* qb  = wob + WELEM;
  short* kb  = qb + NELEM;
  short* vb  = kb + NELEM;
  short* ctx = qb;   // alias: qb dead after qkv_kernel; attn writes ctx after

  dim3 blk(256);
  convert_all<<<dim3(11520), blk, 0, stream>>>(q, k, v, w_q, w_k, w_v, w_o,
                                               qb, kb, vb, wqb, wkb, wvb, wob);
  qkv_kernel<<<dim3(576), blk, 0, stream>>>(qb, kb, vb, wqb, wkb, wvb,
                                            b_q, b_k, b_v, qh, kh, vt);
  attn_kernel<<<dim3(32, 24), blk, 0, stream>>>(qh, kh, vt, ctx);
  o_kernel<<<dim3(384), blk, 0, stream>>>(ctx, wob, b_o, out);
}

// Round 2
// 204.714 us; speedup vs baseline: 1.2423x; 1.2423x over previous
//
#include <hip/hip_runtime.h>
#include <cstdint>

// MultiHeadAttention: B=2 S=2048 D=768 H=12 dk=64, fp32 in/out, bf16 MFMA inside.
//
//   convert_all : q,k,v,w_q,w_k,w_v,w_o fp32 -> bf16              (ws)
//   qkv         : m97-style GEMM: global_load_lds width-16 DMA staging,
//                 single-buffered LDS, 2 barriers/iter, 128x128 tile.
//   attn        : flash attention (no-max softmax), R0 structure (50us).
//                 R2: K/V staging via global_load_lds DMA with PRE-SWIZZLED
//                 global source (m173) -> deletes 4 b128 LDS stores/wave/tile
//                 (attn is LDS-issue-bound: 26 ops ~288cy/wave/tile ~= 46us),
//                 counted vmcnt(4) + raw barriers keep 2 tiles in flight (T4).
//                 (R1's V-direct-from-global regressed 2x: in-step VMEM chain
//                 was latency-exposed at 2 blocks/CU. Reverted.)
//   o           : 64x128-tile DMA GEMM -> fp32 d_out

#define S_LEN 2048
#define NHEAD 12
#define DMODEL 768

typedef short s16x8 __attribute__((ext_vector_type(8)));
typedef float f32x4 __attribute__((ext_vector_type(4)));

#define MFMA16(a, b, c) __builtin_amdgcn_mfma_f32_16x16x32_bf16((a), (b), (c), 0, 0, 0)

__device__ __forceinline__ void lds_dma16(void* lds, const void* g) {
  __builtin_amdgcn_global_load_lds(
      (const __attribute__((address_space(1))) unsigned int*)g,
      (__attribute__((address_space(3))) unsigned int*)lds, 16, 0, 0);
}

__device__ __forceinline__ unsigned int pk_bf16(float a, float b) {
  unsigned int ua = __float_as_uint(a), ub = __float_as_uint(b);
  ua = (ua + 0x7FFFu + ((ua >> 16) & 1u)) >> 16;   // RNE
  ub = (ub + 0x7FFFu + ((ub >> 16) & 1u)) >> 16;
  return ua | (ub << 16);
}
__device__ __forceinline__ short bf16r(float a) {
  unsigned int ua = __float_as_uint(a);
  return (short)((ua + 0x7FFFu + ((ua >> 16) & 1u)) >> 16);
}
// pack hi16(b)<<16 | hi16(a) in ONE v_perm_b32 (trunc; bias cancelled via l)
__device__ __forceinline__ unsigned int pk_trunc(float a, float b) {
  return __builtin_amdgcn_perm(__float_as_uint(b), __float_as_uint(a), 0x07060302u);
}
__device__ __forceinline__ float bf16_floor(float a) {
  return __uint_as_float(__float_as_uint(a) & 0xFFFF0000u);
}

// ---------------------------------------------------------------------------
// All fp32 -> bf16 conversions in ONE launch. 11520 blocks x 256 thr x
// float4/thr: blocks [0,9216) = q,k,v (3072 each); [9216,11520) = 4 weights
// (576 each).
// ---------------------------------------------------------------------------
__global__ __launch_bounds__(256)
void convert_all(const float* __restrict__ q, const float* __restrict__ k,
                 const float* __restrict__ v,
                 const float* __restrict__ w0, const float* __restrict__ w1,
                 const float* __restrict__ w2, const float* __restrict__ w3,
                 short* __restrict__ qb, short* __restrict__ kb,
                 short* __restrict__ vb,
                 short* __restrict__ o0, short* __restrict__ o1,
                 short* __restrict__ o2, short* __restrict__ o3) {
  int b = blockIdx.x;
  const float* src;
  short* dst;
  if (b < 9216) {
    const int s = b / 3072;
    src = (s == 0) ? q : (s == 1) ? k : v;
    dst = (s == 0) ? qb : (s == 1) ? kb : vb;
    b -= s * 3072;
  } else {
    b -= 9216;
    const int s = b / 576;
    src = (s == 0) ? w0 : (s == 1) ? w1 : (s == 2) ? w2 : w3;
    dst = (s == 0) ? o0 : (s == 1) ? o1 : (s == 2) ? o2 : o3;
    b -= s * 576;
  }
  const long i = ((long)b * 256 + threadIdx.x) * 4;
  float4 f = *(const float4*)(src + i);
  uint2 u;
  u.x = pk_bf16(f.x, f.y);
  u.y = pk_bf16(f.z, f.w);
  *(uint2*)(dst + i) = u;
}

// ---------------------------------------------------------------------------
// Fused QKV projection, m97-style. 576 blocks, XCD-swizzled.
// Tile 128x128, BK=32, 4 waves each 64x64 (acc[4][4]).
// Staging: global_load_lds x4 per wave (A 2, B 2), LDS rows of 32 shorts.
// ---------------------------------------------------------------------------
__global__ __launch_bounds__(256)
void qkv_kernel(const short* __restrict__ qb, const short* __restrict__ kb,
                const short* __restrict__ vb,
                const short* __restrict__ wq, const short* __restrict__ wk,
                const short* __restrict__ wv,
                const float* __restrict__ bq, const float* __restrict__ bk,
                const float* __restrict__ bv,
                short* __restrict__ qh, short* __restrict__ kh,
                short* __restrict__ vt) {
  constexpr int K = 768;
  __shared__ short Abuf[128 * 32];   // [row][k], 64B rows
  __shared__ short Bbuf[128 * 32];

  const int L   = blockIdx.x;        // 0..575
  const int xcd = L & 7;
  const int i   = L >> 3;            // 0..71
  const int nt  = i % 6;
  const int pl  = xcd * 12 + i / 6;  // 0..95 (m,z) pair
  const int z   = pl >> 5;           // 32 m-tiles per z
  const int mt  = pl & 31;
  const int m0  = mt * 128;          // token
  const int n0  = nt * 128;          // feature

  const short* A = (z == 0) ? qb : (z == 1) ? kb : vb;
  const short* B = (z == 0) ? wq : (z == 1) ? wk : wv;
  const float* bias = (z == 0) ? bq : (z == 1) ? bk : bv;

  const int tid  = threadIdx.x;
  const int lane = tid & 63;
  const int w    = tid >> 6;
  const int g    = lane >> 4;
  const int c    = lane & 15;
  const int wm   = (w & 1) * 64;
  const int wn   = (w >> 1) * 64;

  // DMA addressing: wave w covers rows [w*32, w*32+32), 2 insts x 16 rows.
  // lane l -> row +l/4, col (l&3)*8; LDS linear dest = base + l*16B.
  const int drow = w * 32 + (lane >> 2);
  const int dcol = (lane & 3) * 8;
  const short* Ag = A + (long)(m0 + drow) * K + dcol;
  const short* Bg = B + (long)(n0 + drow) * K + dcol;
  short* Al0 = &Abuf[w * 1024];
  short* Al1 = &Abuf[w * 1024 + 512];
  short* Bl0 = &Bbuf[w * 1024];
  short* Bl1 = &Bbuf[w * 1024 + 512];

  f32x4 acc[4][4];
#pragma unroll
  for (int a = 0; a < 4; ++a)
#pragma unroll
    for (int b2 = 0; b2 < 4; ++b2) acc[a][b2] = (f32x4){0.f, 0.f, 0.f, 0.f};

  for (int kt = 0; kt < K; kt += 32) {
    lds_dma16(Al0, Ag + kt);
    lds_dma16(Al1, Ag + (long)16 * K + kt);
    lds_dma16(Bl0, Bg + kt);
    lds_dma16(Bl1, Bg + (long)16 * K + kt);
    __syncthreads();   // vmcnt(0) drain: DMA landed

    s16x8 af[4], bf[4];
#pragma unroll
    for (int mb = 0; mb < 4; ++mb)
      af[mb] = *(const s16x8*)&Abuf[(wm + mb * 16 + c) * 32 + g * 8];
#pragma unroll
    for (int nb = 0; nb < 4; ++nb)
      bf[nb] = *(const s16x8*)&Bbuf[(wn + nb * 16 + c) * 32 + g * 8];
#pragma unroll
    for (int mb = 0; mb < 4; ++mb)
#pragma unroll
      for (int nb = 0; nb < 4; ++nb)
        acc[mb][nb] = MFMA16(af[mb], bf[nb], acc[mb][nb]);
    __syncthreads();   // safe to overwrite LDS
  }

  if (z < 2) {
    short* outp = z ? kh : qh;
    const float scale = z ? 1.0f : 0.18033688011112042f;  // log2e/8
#pragma unroll
    for (int mb = 0; mb < 4; ++mb) {
#pragma unroll
      for (int nb = 0; nb < 4; ++nb) {
        const int n = n0 + wn + nb * 16 + c;
        const float bvv = bias[n];
        const int hh = n >> 6, d = n & 63;
#pragma unroll
        for (int r = 0; r < 4; ++r) {
          const int m = m0 + wm + mb * 16 + g * 4 + r;
          const int b2 = m >> 11, s = m & 2047;
          const float val = (acc[mb][nb][r] + bvv) * scale;
          outp[(((long)(b2 * NHEAD + hh) * S_LEN + s) << 6) + d] = bf16r(val);
        }
      }
    }
  } else {  // V: transposed write Vt[b][h][d][t], 4 consecutive t per lane
#pragma unroll
    for (int mb = 0; mb < 4; ++mb) {
#pragma unroll
      for (int nb = 0; nb < 4; ++nb) {
        const int n = n0 + wn + nb * 16 + c;   // feature
        const float bvv = bias[n];
        const int hh = n >> 6, d = n & 63;
        const int m_base = m0 + wm + mb * 16 + g * 4;   // token base
        const int b2 = m_base >> 11, t = m_base & 2047;
        uint2 ov;
        ov.x = pk_bf16(acc[mb][nb][0] + bvv, acc[mb][nb][1] + bvv);
        ov.y = pk_bf16(acc[mb][nb][2] + bvv, acc[mb][nb][3] + bvv);
        *(uint2*)(vt + ((long)(b2 * NHEAD + hh) * 64 + d) * S_LEN + t) = ov;
      }
    }
  }
}

// ---------------------------------------------------------------------------
// Output projection, m97-style 64x128 tile. 384 blocks, XCD-swizzled.
// A = ctx (bf16), B = w_o (bf16), out fp32. Wave tile 32x64, acc[2][4].
// ---------------------------------------------------------------------------
__global__ __launch_bounds__(256)
void o_kernel(const short* __restrict__ ctx, const short* __restrict__ wo,
              const float* __restrict__ bo, float* __restrict__ out) {
  constexpr int K = 768;
  __shared__ short Abuf[64 * 32];
  __shared__ short Bbuf[128 * 32];

  const int L   = blockIdx.x;        // 0..383
  const int xcd = L & 7;
  const int i   = L >> 3;            // 0..47
  const int nt  = i % 6;
  const int mt  = xcd * 8 + i / 6;   // 0..63
  const int m0  = mt * 64;
  const int n0  = nt * 128;

  const int tid  = threadIdx.x;
  const int lane = tid & 63;
  const int w    = tid >> 6;
  const int g    = lane >> 4;
  const int c    = lane & 15;
  const int wm   = (w & 1) * 32;
  const int wn   = (w >> 1) * 64;

  // A: wave w covers rows [w*16, w*16+16), 1 inst. B: rows [w*32,+32), 2.
  const int arow = w * 16 + (lane >> 2);
  const int brow = w * 32 + (lane >> 2);
  const int dcol = (lane & 3) * 8;
  const short* Ag = ctx + (long)(m0 + arow) * K + dcol;
  const short* Bg = wo + (long)(n0 + brow) * K + dcol;
  short* Al = &Abuf[w * 512];
  short* Bl0 = &Bbuf[w * 1024];
  short* Bl1 = &Bbuf[w * 1024 + 512];

  f32x4 acc[2][4];
#pragma unroll
  for (int a = 0; a < 2; ++a)
#pragma unroll
    for (int b2 = 0; b2 < 4; ++b2) acc[a][b2] = (f32x4){0.f, 0.f, 0.f, 0.f};

  for (int kt = 0; kt < K; kt += 32) {
    lds_dma16(Al, Ag + kt);
    lds_dma16(Bl0, Bg + kt);
    lds_dma16(Bl1, Bg + (long)16 * K + kt);
    __syncthreads();

    s16x8 af[2], bf[4];
#pragma unroll
    for (int mb = 0; mb < 2; ++mb)
      af[mb] = *(const s16x8*)&Abuf[(wm + mb * 16 + c) * 32 + g * 8];
#pragma unroll
    for (int nb = 0; nb < 4; ++nb)
      bf[nb] = *(const s16x8*)&Bbuf[(wn + nb * 16 + c) * 32 + g * 8];
#pragma unroll
    for (int mb = 0; mb < 2; ++mb)
#pragma unroll
      for (int nb = 0; nb < 4; ++nb)
        acc[mb][nb] = MFMA16(af[mb], bf[nb], acc[mb][nb]);
    __syncthreads();
  }

#pragma unroll
  for (int mb = 0; mb < 2; ++mb) {
#pragma unroll
    for (int nb = 0; nb < 4; ++nb) {
      const int n = n0 + wn + nb * 16 + c;
      const float bvv = bo[n];
#pragma unroll
      for (int r = 0; r < 4; ++r) {
        const int m = m0 + wm + mb * 16 + g * 4 + r;
        out[(long)m * DMODEL + n] = acc[mb][nb][r] + bvv;
      }
    }
  }
}

// ---------------------------------------------------------------------------
// Flash attention, no-max softmax. R0 structure; R2: DMA-staged K/V.
//
// LDS layout (per tile, per buffer): kbuf rows t (64), 8 chunks of 16B;
// chunk position p at row r holds global chunk p^(r&7)  (XOR swizzle).
// DMA reproduces this with LINEAR LDS dest + pre-swizzled global source:
// thread -> row r = i*32 + w*8 + (lane>>3), position lane&7, source chunk
// (lane&7)^(lane>>3) == position^(r&7).   (vbuf identical with rows = d.)
//
// Pipeline: 2 tiles of DMA in flight; per tile:
//   s_waitcnt vmcnt(4)  (tile j landed; j+1 still in flight)
//   s_barrier           (all threads' DMA for tile j visible)
//   step(buf[p])        (all LDS reads consumed by MFMAs before barrier)
//   s_barrier           (all waves done reading buf[p])
//   DMA(buf[p], tile j+2)
// ---------------------------------------------------------------------------
__global__ __launch_bounds__(256)
void attn_kernel(const short* __restrict__ Qh, const short* __restrict__ Kh,
                 const short* __restrict__ Vt, short* __restrict__ Ctx) {
  __shared__ short kbuf[2][64 * 64];      // swizzled [t][d]
  __shared__ short vbuf[2][64 * 64];      // swizzled [d][t]
  __shared__ short pbuf[4][16 * 64];      // per-wave [s][t], XOR-swizzled

  const int tid  = threadIdx.x;
  const int lane = tid & 63;
  const int w    = tid >> 6;
  const int g    = lane >> 4;
  const int c    = lane & 15;
  const int bh   = blockIdx.y;            // 0..23
  const int qs0  = blockIdx.x * 64;
  const long base = (long)bh * S_LEN * 64;
  const short* Qb = Qh + base;
  const short* Kb = Kh + base;
  const short* Vb = Vt + base;

  const long qrow = (long)(qs0 + w * 16 + c) * 64;
  const s16x8 qf0 = *(const s16x8*)(Qb + qrow + g * 8);
  const s16x8 qf1 = *(const s16x8*)(Qb + qrow + 32 + g * 8);

  f32x4 co[4];
#pragma unroll
  for (int i = 0; i < 4; ++i) co[i] = (f32x4){0.f, 0.f, 0.f, 0.f};
  float l_lane = 0.f;

  // ---- DMA staging addressing (pre-swizzled source, linear LDS dest) ----
  const int drow  = w * 8 + (lane >> 3);              // row within 32-row group
  const int dchk  = ((lane & 7) ^ (lane >> 3)) * 8;   // swizzled 16B chunk (shorts)
  const short* kdma = Kb + (long)drow * 64 + dchk;    // + (t0 + i*32)*64
  const short* vdma = Vb + (long)drow * S_LEN + dchk; // + i*32*S_LEN + t0

  auto dma_tile = [&](int p, long t0) {
#pragma unroll
    for (int i = 0; i < 2; ++i) {
      lds_dma16(&kbuf[p][(i * 32 + w * 8) * 64], kdma + (t0 + i * 32) * 64);
      lds_dma16(&vbuf[p][(i * 32 + w * 8) * 64], vdma + (long)i * 32 * S_LEN + t0);
    }
  };

  // ---- read-side constants (unchanged XOR layout) ----
  const int cw   = c & 7;
  const int rg0  = ((g)     ^ cw) * 8;
  const int rg1  = ((4 + g) ^ cw) * 8;
  const int pr0 = c * 64 + ((g ^ cw) * 8);
  const int pr1 = c * 64 + (((4 + g) ^ cw) * 8);

  auto step = [&](const short* kb2, const short* vb2) {
    f32x4 st[4];
#pragma unroll
    for (int mb = 0; mb < 4; ++mb) {
      const s16x8 k0 = *(const s16x8*)&kb2[(mb * 16 + c) * 64 + rg0];
      const s16x8 k1 = *(const s16x8*)&kb2[(mb * 16 + c) * 64 + rg1];
      f32x4 z = (f32x4){0.f, 0.f, 0.f, 0.f};
      z = MFMA16(k0, qf0, z);
      z = MFMA16(k1, qf1, z);
      st[mb] = z;
    }
#pragma unroll
    for (int mb = 0; mb < 4; ++mb) {
      float p0 = __builtin_amdgcn_exp2f(st[mb][0]);
      float p1 = __builtin_amdgcn_exp2f(st[mb][1]);
      float p2 = __builtin_amdgcn_exp2f(st[mb][2]);
      float p3 = __builtin_amdgcn_exp2f(st[mb][3]);
      l_lane += bf16_floor(p0) + bf16_floor(p1) + bf16_floor(p2) + bf16_floor(p3);
      uint2 pw;
      pw.x = pk_trunc(p0, p1);
      pw.y = pk_trunc(p2, p3);
      const int pg = ((2 * mb + (g >> 1)) ^ cw) * 8 + (g & 1) * 4;
      *(uint2*)&pbuf[w][c * 64 + pg] = pw;
    }
    const s16x8 pb0 = *(const s16x8*)&pbuf[w][pr0];
    const s16x8 pb1 = *(const s16x8*)&pbuf[w][pr1];
#pragma unroll
    for (int db = 0; db < 4; ++db) {
      const s16x8 v0 = *(const s16x8*)&vb2[(db * 16 + c) * 64 + rg0];
      const s16x8 v1 = *(const s16x8*)&vb2[(db * 16 + c) * 64 + rg1];
      __builtin_amdgcn_s_setprio(1);
      co[db] = MFMA16(v0, pb0, co[db]);
      co[db] = MFMA16(v1, pb1, co[db]);
      __builtin_amdgcn_s_setprio(0);
    }
  };

  constexpr int NT = S_LEN / 64;   // 32 tiles
  dma_tile(0, 0);
  dma_tile(1, 64);
  int p = 0;
  for (int j = 0; j < NT; ++j) {
    asm volatile("s_waitcnt vmcnt(4)" ::: "memory");  // tile j landed
    __builtin_amdgcn_s_barrier();                     // visible to all waves
    __builtin_amdgcn_sched_barrier(0);                // no ds_read hoisting
    step(kbuf[p], vbuf[p]);
    __builtin_amdgcn_s_barrier();                     // all done reading buf[p]
    const long tn = (j + 2 < NT) ? (long)(j + 2) * 64 : 0;
    dma_tile(p, tn);                                  // refill (2-deep pipe)
    p ^= 1;
  }

  float rs = l_lane;
  rs += __shfl_xor(rs, 16);
  rs += __shfl_xor(rs, 32);
  const float invl = 1.f / rs;

  const int hh = bh % NHEAD;
  const long tok = (long)(bh / NHEAD) * S_LEN + qs0 + w * 16 + c;
#pragma unroll
  for (int db = 0; db < 4; ++db) {
    uint2 ov;
    ov.x = pk_bf16(co[db][0] * invl, co[db][1] * invl);
    ov.y = pk_bf16(co[db][2] * invl, co[db][3] * invl);
    *(uint2*)(Ctx + tok * DMODEL + hh * 64 + db * 16 + g * 4) = ov;
  }
}

// ---------------------------------------------------------------------------
extern "C" void kernel_launch(void* const* d_in, const int* in_sizes, int n_in,
                              void* d_out, int out_size, void* d_ws, size_t ws_size,
                              hipStream_t stream) {
  const float* q   = (const float*)d_in[0];
  const float* k   = (const float*)d_in[1];
  const float* v   = (const float*)d_in[2];
  const float* w_q = (const float*)d_in[3];
  const float* b_q = (const float*)d_in[4];
  const float* w_k = (const float*)d_in[5];
  const float* b_k = (const float*)d_in[6];
  const float* w_v = (const float*)d_in[7];
  const float* b_v = (const float*)d_in[8];
  const float* w_o = (const float*)d_in[9];
  const float* b_o = (const float*)d_in[10];
  float* out = (float*)d_out;

  const long NELEM = (long)2 * NHEAD * S_LEN * 64;  // 3,145,728
  const long WELEM = (long)DMODEL * DMODEL;         // 589,824
  short* qh  = (short*)d_ws;
  short* kh  = qh + NELEM;
  short* vt  = kh + NELEM;
  short* wqb = vt + NELEM;
  short* wkb = wqb + WELEM;
  short* wvb = wkb + WELEM;
  short* wob = wvb + WELEM;
  short* qb  = wob + WELEM;
  short* kb  = qb + NELEM;
  short* vb  = kb + NELEM;
  short* ctx = qb;   // alias: qb dead after qkv_kernel; attn writes ctx after

  dim3 blk(256);
  convert_all<<<dim3(11520), blk, 0, stream>>>(q, k, v, w_q, w_k, w_v, w_o,
                                               qb, kb, vb, wqb, wkb, wvb, wob);
  qkv_kernel<<<dim3(576), blk, 0, stream>>>(qb, kb, vb, wqb, wkb, wvb,
                                            b_q, b_k, b_v, qh, kh, vt);
  attn_kernel<<<dim3(32, 24), blk, 0, stream>>>(qh, kh, vt, ctx);
  o_kernel<<<dim3(384), blk, 0, stream>>>(ctx, wob, b_o, out);
}

// Round 3
// 193.100 us; speedup vs baseline: 1.3170x; 1.0601x over previous
//
#include <hip/hip_runtime.h>
#include <cstdint>

// MultiHeadAttention: B=2 S=2048 D=768 H=12 dk=64, fp32 in/out, bf16 MFMA inside.
//
//   convert_all : q,k,v,w_q,w_k,w_v,w_o fp32 -> bf16              (ws)
//   qkv         : m97-style GEMM: global_load_lds width-16 DMA staging,
//                 single-buffered LDS, 2 barriers/iter, 128x128 tile.
//   attn        : flash attention (no-max softmax).
//                 R3: 32x32x16 MFMA + in-register P (permlane32_swap).
//                 R0 was LDS-pipe-bound (model: 106k LDS-cyc/CU = 44us ~= 50
//                 measured). 32x32 A-frags cover 32 rows/b128 (2x LDS
//                 efficiency); swapped-QK makes P fully lane-local (col=lane&31)
//                 so pbuf is deleted: P->PV fragments built with 16 pk + 8
//                 v_permlane32_swap_b32 in registers. 20 LDS ops per 32 q-rows
//                 vs R0's 52. Staging = R0's known-good reg-staged XOR path.
//   o           : 64x128-tile DMA GEMM -> fp32 d_out

#define S_LEN 2048
#define NHEAD 12
#define DMODEL 768

typedef short s16x8 __attribute__((ext_vector_type(8)));
typedef float f32x4 __attribute__((ext_vector_type(4)));
typedef float f32x16 __attribute__((ext_vector_type(16)));

#define MFMA16(a, b, c) __builtin_amdgcn_mfma_f32_16x16x32_bf16((a), (b), (c), 0, 0, 0)
#define MFMA32(a, b, c) __builtin_amdgcn_mfma_f32_32x32x16_bf16((a), (b), (c), 0, 0, 0)

__device__ __forceinline__ void lds_dma16(void* lds, const void* g) {
  __builtin_amdgcn_global_load_lds(
      (const __attribute__((address_space(1))) unsigned int*)g,
      (__attribute__((address_space(3))) unsigned int*)lds, 16, 0, 0);
}

__device__ __forceinline__ unsigned int pk_bf16(float a, float b) {
  unsigned int ua = __float_as_uint(a), ub = __float_as_uint(b);
  ua = (ua + 0x7FFFu + ((ua >> 16) & 1u)) >> 16;   // RNE
  ub = (ub + 0x7FFFu + ((ub >> 16) & 1u)) >> 16;
  return ua | (ub << 16);
}
__device__ __forceinline__ short bf16r(float a) {
  unsigned int ua = __float_as_uint(a);
  return (short)((ua + 0x7FFFu + ((ua >> 16) & 1u)) >> 16);
}
// pack hi16(b)<<16 | hi16(a) in ONE v_perm_b32 (trunc; bias cancelled via l)
__device__ __forceinline__ unsigned int pk_trunc(float a, float b) {
  return __builtin_amdgcn_perm(__float_as_uint(b), __float_as_uint(a), 0x07060302u);
}
__device__ __forceinline__ float bf16_floor(float a) {
  return __uint_as_float(__float_as_uint(a) & 0xFFFF0000u);
}

// ---------------------------------------------------------------------------
// All fp32 -> bf16 conversions in ONE launch. 11520 blocks x 256 thr x
// float4/thr: blocks [0,9216) = q,k,v (3072 each); [9216,11520) = 4 weights
// (576 each).
// ---------------------------------------------------------------------------
__global__ __launch_bounds__(256)
void convert_all(const float* __restrict__ q, const float* __restrict__ k,
                 const float* __restrict__ v,
                 const float* __restrict__ w0, const float* __restrict__ w1,
                 const float* __restrict__ w2, const float* __restrict__ w3,
                 short* __restrict__ qb, short* __restrict__ kb,
                 short* __restrict__ vb,
                 short* __restrict__ o0, short* __restrict__ o1,
                 short* __restrict__ o2, short* __restrict__ o3) {
  int b = blockIdx.x;
  const float* src;
  short* dst;
  if (b < 9216) {
    const int s = b / 3072;
    src = (s == 0) ? q : (s == 1) ? k : v;
    dst = (s == 0) ? qb : (s == 1) ? kb : vb;
    b -= s * 3072;
  } else {
    b -= 9216;
    const int s = b / 576;
    src = (s == 0) ? w0 : (s == 1) ? w1 : (s == 2) ? w2 : w3;
    dst = (s == 0) ? o0 : (s == 1) ? o1 : (s == 2) ? o2 : o3;
    b -= s * 576;
  }
  const long i = ((long)b * 256 + threadIdx.x) * 4;
  float4 f = *(const float4*)(src + i);
  uint2 u;
  u.x = pk_bf16(f.x, f.y);
  u.y = pk_bf16(f.z, f.w);
  *(uint2*)(dst + i) = u;
}

// ---------------------------------------------------------------------------
// Fused QKV projection, m97-style. 576 blocks, XCD-swizzled.
// Tile 128x128, BK=32, 4 waves each 64x64 (acc[4][4]).
// Staging: global_load_lds x4 per wave (A 2, B 2), LDS rows of 32 shorts.
// ---------------------------------------------------------------------------
__global__ __launch_bounds__(256)
void qkv_kernel(const short* __restrict__ qb, const short* __restrict__ kb,
                const short* __restrict__ vb,
                const short* __restrict__ wq, const short* __restrict__ wk,
                const short* __restrict__ wv,
                const float* __restrict__ bq, const float* __restrict__ bk,
                const float* __restrict__ bv,
                short* __restrict__ qh, short* __restrict__ kh,
                short* __restrict__ vt) {
  constexpr int K = 768;
  __shared__ short Abuf[128 * 32];   // [row][k], 64B rows
  __shared__ short Bbuf[128 * 32];

  const int L   = blockIdx.x;        // 0..575
  const int xcd = L & 7;
  const int i   = L >> 3;            // 0..71
  const int nt  = i % 6;
  const int pl  = xcd * 12 + i / 6;  // 0..95 (m,z) pair
  const int z   = pl >> 5;           // 32 m-tiles per z
  const int mt  = pl & 31;
  const int m0  = mt * 128;          // token
  const int n0  = nt * 128;          // feature

  const short* A = (z == 0) ? qb : (z == 1) ? kb : vb;
  const short* B = (z == 0) ? wq : (z == 1) ? wk : wv;
  const float* bias = (z == 0) ? bq : (z == 1) ? bk : bv;

  const int tid  = threadIdx.x;
  const int lane = tid & 63;
  const int w    = tid >> 6;
  const int g    = lane >> 4;
  const int c    = lane & 15;
  const int wm   = (w & 1) * 64;
  const int wn   = (w >> 1) * 64;

  // DMA addressing: wave w covers rows [w*32, w*32+32), 2 insts x 16 rows.
  // lane l -> row +l/4, col (l&3)*8; LDS linear dest = base + l*16B.
  const int drow = w * 32 + (lane >> 2);
  const int dcol = (lane & 3) * 8;
  const short* Ag = A + (long)(m0 + drow) * K + dcol;
  const short* Bg = B + (long)(n0 + drow) * K + dcol;
  short* Al0 = &Abuf[w * 1024];
  short* Al1 = &Abuf[w * 1024 + 512];
  short* Bl0 = &Bbuf[w * 1024];
  short* Bl1 = &Bbuf[w * 1024 + 512];

  f32x4 acc[4][4];
#pragma unroll
  for (int a = 0; a < 4; ++a)
#pragma unroll
    for (int b2 = 0; b2 < 4; ++b2) acc[a][b2] = (f32x4){0.f, 0.f, 0.f, 0.f};

  for (int kt = 0; kt < K; kt += 32) {
    lds_dma16(Al0, Ag + kt);
    lds_dma16(Al1, Ag + (long)16 * K + kt);
    lds_dma16(Bl0, Bg + kt);
    lds_dma16(Bl1, Bg + (long)16 * K + kt);
    __syncthreads();   // vmcnt(0) drain: DMA landed

    s16x8 af[4], bf[4];
#pragma unroll
    for (int mb = 0; mb < 4; ++mb)
      af[mb] = *(const s16x8*)&Abuf[(wm + mb * 16 + c) * 32 + g * 8];
#pragma unroll
    for (int nb = 0; nb < 4; ++nb)
      bf[nb] = *(const s16x8*)&Bbuf[(wn + nb * 16 + c) * 32 + g * 8];
#pragma unroll
    for (int mb = 0; mb < 4; ++mb)
#pragma unroll
      for (int nb = 0; nb < 4; ++nb)
        acc[mb][nb] = MFMA16(af[mb], bf[nb], acc[mb][nb]);
    __syncthreads();   // safe to overwrite LDS
  }

  if (z < 2) {
    short* outp = z ? kh : qh;
    const float scale = z ? 1.0f : 0.18033688011112042f;  // log2e/8
#pragma unroll
    for (int mb = 0; mb < 4; ++mb) {
#pragma unroll
      for (int nb = 0; nb < 4; ++nb) {
        const int n = n0 + wn + nb * 16 + c;
        const float bvv = bias[n];
        const int hh = n >> 6, d = n & 63;
#pragma unroll
        for (int r = 0; r < 4; ++r) {
          const int m = m0 + wm + mb * 16 + g * 4 + r;
          const int b2 = m >> 11, s = m & 2047;
          const float val = (acc[mb][nb][r] + bvv) * scale;
          outp[(((long)(b2 * NHEAD + hh) * S_LEN + s) << 6) + d] = bf16r(val);
        }
      }
    }
  } else {  // V: transposed write Vt[b][h][d][t], 4 consecutive t per lane
#pragma unroll
    for (int mb = 0; mb < 4; ++mb) {
#pragma unroll
      for (int nb = 0; nb < 4; ++nb) {
        const int n = n0 + wn + nb * 16 + c;   // feature
        const float bvv = bias[n];
        const int hh = n >> 6, d = n & 63;
        const int m_base = m0 + wm + mb * 16 + g * 4;   // token base
        const int b2 = m_base >> 11, t = m_base & 2047;
        uint2 ov;
        ov.x = pk_bf16(acc[mb][nb][0] + bvv, acc[mb][nb][1] + bvv);
        ov.y = pk_bf16(acc[mb][nb][2] + bvv, acc[mb][nb][3] + bvv);
        *(uint2*)(vt + ((long)(b2 * NHEAD + hh) * 64 + d) * S_LEN + t) = ov;
      }
    }
  }
}

// ---------------------------------------------------------------------------
// Output projection, m97-style 64x128 tile. 384 blocks, XCD-swizzled.
// A = ctx (bf16), B = w_o (bf16), out fp32. Wave tile 32x64, acc[2][4].
// ---------------------------------------------------------------------------
__global__ __launch_bounds__(256)
void o_kernel(const short* __restrict__ ctx, const short* __restrict__ wo,
              const float* __restrict__ bo, float* __restrict__ out) {
  constexpr int K = 768;
  __shared__ short Abuf[64 * 32];
  __shared__ short Bbuf[128 * 32];

  const int L   = blockIdx.x;        // 0..383
  const int xcd = L & 7;
  const int i   = L >> 3;            // 0..47
  const int nt  = i % 6;
  const int mt  = xcd * 8 + i / 6;   // 0..63
  const int m0  = mt * 64;
  const int n0  = nt * 128;

  const int tid  = threadIdx.x;
  const int lane = tid & 63;
  const int w    = tid >> 6;
  const int g    = lane >> 4;
  const int c    = lane & 15;
  const int wm   = (w & 1) * 32;
  const int wn   = (w >> 1) * 64;

  // A: wave w covers rows [w*16, w*16+16), 1 inst. B: rows [w*32,+32), 2.
  const int arow = w * 16 + (lane >> 2);
  const int brow = w * 32 + (lane >> 2);
  const int dcol = (lane & 3) * 8;
  const short* Ag = ctx + (long)(m0 + arow) * K + dcol;
  const short* Bg = wo + (long)(n0 + brow) * K + dcol;
  short* Al = &Abuf[w * 512];
  short* Bl0 = &Bbuf[w * 1024];
  short* Bl1 = &Bbuf[w * 1024 + 512];

  f32x4 acc[2][4];
#pragma unroll
  for (int a = 0; a < 2; ++a)
#pragma unroll
    for (int b2 = 0; b2 < 4; ++b2) acc[a][b2] = (f32x4){0.f, 0.f, 0.f, 0.f};

  for (int kt = 0; kt < K; kt += 32) {
    lds_dma16(Al, Ag + kt);
    lds_dma16(Bl0, Bg + kt);
    lds_dma16(Bl1, Bg + (long)16 * K + kt);
    __syncthreads();

    s16x8 af[2], bf[4];
#pragma unroll
    for (int mb = 0; mb < 2; ++mb)
      af[mb] = *(const s16x8*)&Abuf[(wm + mb * 16 + c) * 32 + g * 8];
#pragma unroll
    for (int nb = 0; nb < 4; ++nb)
      bf[nb] = *(const s16x8*)&Bbuf[(wn + nb * 16 + c) * 32 + g * 8];
#pragma unroll
    for (int mb = 0; mb < 2; ++mb)
#pragma unroll
      for (int nb = 0; nb < 4; ++nb)
        acc[mb][nb] = MFMA16(af[mb], bf[nb], acc[mb][nb]);
    __syncthreads();
  }

#pragma unroll
  for (int mb = 0; mb < 2; ++mb) {
#pragma unroll
    for (int nb = 0; nb < 4; ++nb) {
      const int n = n0 + wn + nb * 16 + c;
      const float bvv = bo[n];
#pragma unroll
      for (int r = 0; r < 4; ++r) {
        const int m = m0 + wm + mb * 16 + g * 4 + r;
        out[(long)m * DMODEL + n] = acc[mb][nb][r] + bvv;
      }
    }
  }
}

// ---------------------------------------------------------------------------
// Flash attention, no-max softmax. R3: 32x32x16 MFMA, in-register P.
//
// 4 waves/block, QBLK=64: wave = (rh = w>>1: q-rows rh*32..+32) x
// (par = w&1: even/odd KV tiles). Per phase (2 tiles) each wave does ONE
// 32-row x 64-t step on its parity buffer. Partial co/l merged across
// parities through LDS at the end.
//
// 32x32x16 layouts (A/B: lane&31 = m/n, k = (lane>>5)*8 + j; C/D verified
// m74: col=lane&31, row=(r&3)+8*(r>>2)+4*(lane>>5)):
//   QK: mfma(A=K[t][d], B=Q[d][q]) -> S[t][q]: lane q=lane&31 holds 32 t's.
//   P packs: pk_trunc pairs (t0,t1).. -> 8 u32/Mtile; v_permlane32_swap
//   exchanges lane-halves so each PV B-frag (k=t slice of 16) lands in regs.
//   PV: mfma(A=V[d][t], B=P[t][q]) -> co[d][q].
// K/V staging: R0's reg-staged XOR path (t&7-XOR'd 16B chunks), 2 tiles/phase.
// ---------------------------------------------------------------------------
__global__ __launch_bounds__(256, 3)
void attn_kernel(const short* __restrict__ Qh, const short* __restrict__ Kh,
                 const short* __restrict__ Vt, short* __restrict__ Ctx) {
  __shared__ short kbuf[2][64 * 64];      // swizzled [t][d], per parity
  __shared__ short vbuf[2][64 * 64];      // swizzled [d][t], per parity

  const int tid  = threadIdx.x;
  const int lane = tid & 63;
  const int w    = tid >> 6;
  const int par  = w & 1;                 // tile parity
  const int rh   = w >> 1;                // q-row half
  const int q32  = lane & 31;
  const int hi   = lane >> 5;
  const int bh   = blockIdx.y;            // 0..23
  const int qs0  = blockIdx.x * 64;
  const long base = (long)bh * S_LEN * 64;
  const short* Qb = Qh + base;
  const short* Kb = Kh + base;
  const short* Vb = Vt + base;

  // Q fragments (B operand): n=q32, k=d = db*16 + hi*8 + j
  const long qrow = (long)(qs0 + rh * 32 + q32) * 64;
  s16x8 qf[4];
#pragma unroll
  for (int db = 0; db < 4; ++db)
    qf[db] = *(const s16x8*)(Qb + qrow + db * 16 + hi * 8);

  f32x16 co0, co1;
#pragma unroll
  for (int i = 0; i < 16; ++i) { co0[i] = 0.f; co1[i] = 0.f; }
  float l_lane = 0.f;

  // ---- staging identities (R0) ----
  const int srow = tid >> 2;           // 0..63 (t-row for K, d-row for V)
  const int sq   = tid & 3;
  const int sw   = srow & 7;
  const int sg0  = ((2 * sq)     ^ sw) * 8;
  const int sg1  = ((2 * sq + 1) ^ sw) * 8;
  const short* kg = Kb + (long)srow * 64 + sq * 16;
  const short* vg = Vb + (long)srow * S_LEN + sq * 16;

  uint4 rkE0, rkE1, rvE0, rvE1, rkO0, rkO1, rvO0, rvO1;
  auto fetch_pair = [&](long tE, long tO) {
    rkE0 = *(const uint4*)(kg + tE * 64);
    rkE1 = *(const uint4*)(kg + tE * 64 + 8);
    rvE0 = *(const uint4*)(vg + tE);
    rvE1 = *(const uint4*)(vg + tE + 8);
    rkO0 = *(const uint4*)(kg + tO * 64);
    rkO1 = *(const uint4*)(kg + tO * 64 + 8);
    rvO0 = *(const uint4*)(vg + tO);
    rvO1 = *(const uint4*)(vg + tO + 8);
  };
  auto store_pair = [&]() {
    *(uint4*)&kbuf[0][srow * 64 + sg0] = rkE0;
    *(uint4*)&kbuf[0][srow * 64 + sg1] = rkE1;
    *(uint4*)&vbuf[0][srow * 64 + sg0] = rvE0;
    *(uint4*)&vbuf[0][srow * 64 + sg1] = rvE1;
    *(uint4*)&kbuf[1][srow * 64 + sg0] = rkO0;
    *(uint4*)&kbuf[1][srow * 64 + sg1] = rkO1;
    *(uint4*)&vbuf[1][srow * 64 + sg0] = rvO0;
    *(uint4*)&vbuf[1][srow * 64 + sg1] = rvO1;
  };

  // ---- read-side precomputed offsets ----
  const int tw = lane & 7;
  int c4[4];
#pragma unroll
  for (int i = 0; i < 4; ++i) c4[i] = ((2 * i + hi) ^ tw) * 8;
  const int row0 = q32 * 64;          // Mtile0 / dtile0 (shorts)
  const int row1 = (32 + q32) * 64;   // Mtile1 / dtile1
  const short* kb2 = kbuf[par];
  const short* vb2 = vbuf[par];

  // P->B-frag builder: words [a', b', c', d'] after two permlane32_swaps.
  auto mkfrag = [&](unsigned a, unsigned b, unsigned c, unsigned d) -> s16x8 {
    asm("v_permlane32_swap_b32 %0, %1" : "+v"(a), "+v"(c));
    asm("v_permlane32_swap_b32 %0, %1" : "+v"(b), "+v"(d));
    uint4 u;
    u.x = a; u.y = b; u.z = c; u.w = d;
    return __builtin_bit_cast(s16x8, u);
  };

  auto step = [&]() {
    // QK^T: S[t][q], t split in two 32-row Mtiles
    f32x16 s0, s1;
#pragma unroll
    for (int i = 0; i < 16; ++i) { s0[i] = 0.f; s1[i] = 0.f; }
    __builtin_amdgcn_s_setprio(1);
#pragma unroll
    for (int db = 0; db < 4; ++db) {
      const s16x8 k0 = *(const s16x8*)&kb2[row0 + c4[db]];
      const s16x8 k1 = *(const s16x8*)&kb2[row1 + c4[db]];
      s0 = MFMA32(k0, qf[db], s0);
      s1 = MFMA32(k1, qf[db], s1);
    }
    __builtin_amdgcn_s_setprio(0);
    // exp2 + l + pack (pairs are t-consecutive: regs (2i, 2i+1))
    unsigned pk0[8], pk1[8];
#pragma unroll
    for (int i = 0; i < 8; ++i) {
      float a0 = __builtin_amdgcn_exp2f(s0[2 * i]);
      float b0 = __builtin_amdgcn_exp2f(s0[2 * i + 1]);
      float a1 = __builtin_amdgcn_exp2f(s1[2 * i]);
      float b1 = __builtin_amdgcn_exp2f(s1[2 * i + 1]);
      l_lane += (bf16_floor(a0) + bf16_floor(b0)) +
                (bf16_floor(a1) + bf16_floor(b1));
      pk0[i] = pk_trunc(a0, b0);
      pk1[i] = pk_trunc(a1, b1);
    }
    // B-frags: slice0 t0..15 (pk0[0..3]), slice1 t16..31 (pk0[4..7]),
    //          slice2 t32..47 (pk1[0..3]), slice3 t48..63 (pk1[4..7])
    s16x8 pf0 = mkfrag(pk0[0], pk0[1], pk0[2], pk0[3]);
    s16x8 pf1 = mkfrag(pk0[4], pk0[5], pk0[6], pk0[7]);
    s16x8 pf2 = mkfrag(pk1[0], pk1[1], pk1[2], pk1[3]);
    s16x8 pf3 = mkfrag(pk1[4], pk1[5], pk1[6], pk1[7]);
    // PV: co[d][q] += V[d][t] * P[t][q]
    __builtin_amdgcn_s_setprio(1);
#pragma unroll
    for (int sl = 0; sl < 4; ++sl) {
      const s16x8 v0 = *(const s16x8*)&vb2[row0 + c4[sl]];
      const s16x8 v1 = *(const s16x8*)&vb2[row1 + c4[sl]];
      const s16x8 pf = (sl == 0) ? pf0 : (sl == 1) ? pf1 : (sl == 2) ? pf2 : pf3;
      co0 = MFMA32(v0, pf, co0);
      co1 = MFMA32(v1, pf, co1);
    }
    __builtin_amdgcn_s_setprio(0);
  };

  constexpr int NT = S_LEN / 64;   // 32 tiles, 16 phases
  fetch_pair(0, 64);
  store_pair();
  for (int ph = 0; ph < NT / 2; ++ph) {
    __syncthreads();                               // both buffers ready
    const long tE = (2 * ph + 2 < NT) ? (long)(2 * ph + 2) * 64 : 0;
    const long tO = (2 * ph + 3 < NT) ? (long)(2 * ph + 3) * 64 : 0;
    fetch_pair(tE, tO);                            // overlap with step
    step();                                        // wave's parity tile
    __syncthreads();                               // all done reading
    store_pair();                                  // refill both buffers
  }

  // l: combine the two t-half lanes (same q) of this wave's tiles
  float rs = l_lane + __shfl_xor(l_lane, 32);

  // ---- cross-parity merge via LDS (stride 36 floats = 144B, 16B-aligned) ----
  __syncthreads();   // staging stores of last phase done; safe to reuse
  float* mbuf = (float*)((rh == 0) ? (short*)kbuf : (short*)vbuf);
  float* mp = mbuf + lane * 36;
  if (par) {
#pragma unroll
    for (int i = 0; i < 4; ++i) {
      *(float4*)(mp + 4 * i)      = make_float4(co0[4*i], co0[4*i+1], co0[4*i+2], co0[4*i+3]);
      *(float4*)(mp + 16 + 4 * i) = make_float4(co1[4*i], co1[4*i+1], co1[4*i+2], co1[4*i+3]);
    }
    mp[32] = rs;
  }
  __syncthreads();
  if (!par) {
#pragma unroll
    for (int i = 0; i < 4; ++i) {
      float4 a = *(const float4*)(mp + 4 * i);
      float4 b = *(const float4*)(mp + 16 + 4 * i);
      co0[4*i] += a.x; co0[4*i+1] += a.y; co0[4*i+2] += a.z; co0[4*i+3] += a.w;
      co1[4*i] += b.x; co1[4*i+1] += b.y; co1[4*i+2] += b.z; co1[4*i+3] += b.w;
    }
    rs += mp[32];
    const float invl = 1.f / rs;

    const int hh = bh % NHEAD;
    const long tok = (long)(bh / NHEAD) * S_LEN + qs0 + rh * 32 + q32;
    short* outp = Ctx + tok * DMODEL + hh * 64;
    // reg r -> d = (r&3) + 8*(r>>2) + 4*hi (+32 for co1)
#pragma unroll
    for (int rq = 0; rq < 4; ++rq) {
      const int d0 = 8 * rq + 4 * hi;
      uint2 ov;
      ov.x = pk_bf16(co0[4*rq] * invl, co0[4*rq+1] * invl);
      ov.y = pk_bf16(co0[4*rq+2] * invl, co0[4*rq+3] * invl);
      *(uint2*)(outp + d0) = ov;
      uint2 ov2;
      ov2.x = pk_bf16(co1[4*rq] * invl, co1[4*rq+1] * invl);
      ov2.y = pk_bf16(co1[4*rq+2] * invl, co1[4*rq+3] * invl);
      *(uint2*)(outp + 32 + d0) = ov2;
    }
  }
}

// ---------------------------------------------------------------------------
extern "C" void kernel_launch(void* const* d_in, const int* in_sizes, int n_in,
                              void* d_out, int out_size, void* d_ws, size_t ws_size,
                              hipStream_t stream) {
  const float* q   = (const float*)d_in[0];
  const float* k   = (const float*)d_in[1];
  const float* v   = (const float*)d_in[2];
  const float* w_q = (const float*)d_in[3];
  const float* b_q = (const float*)d_in[4];
  const float* w_k = (const float*)d_in[5];
  const float* b_k = (const float*)d_in[6];
  const float* w_v = (const float*)d_in[7];
  const float* b_v = (const float*)d_in[8];
  const float* w_o = (const float*)d_in[9];
  const float* b_o = (const float*)d_in[10];
  float* out = (float*)d_out;

  const long NELEM = (long)2 * NHEAD * S_LEN * 64;  // 3,145,728
  const long WELEM = (long)DMODEL * DMODEL;         // 589,824
  short* qh  = (short*)d_ws;
  short* kh  = qh + NELEM;
  short* vt  = kh + NELEM;
  short* wqb = vt + NELEM;
  short* wkb = wqb + WELEM;
  short* wvb = wkb + WELEM;
  short* wob = wvb + WELEM;
  short* qb  = wob + WELEM;
  short* kb  = qb + NELEM;
  short* vb  = kb + NELEM;
  short* ctx = qb;   // alias: qb dead after qkv_kernel; attn writes ctx after

  dim3 blk(256);
  convert_all<<<dim3(11520), blk, 0, stream>>>(q, k, v, w_q, w_k, w_v, w_o,
                                               qb, kb, vb, wqb, wkb, wvb, wob);
  qkv_kernel<<<dim3(576), blk, 0, stream>>>(qb, kb, vb, wqb, wkb, wvb,
                                            b_q, b_k, b_v, qh, kh, vt);
  attn_kernel<<<dim3(32, 24), blk, 0, stream>>>(qh, kh, vt, ctx);
  o_kernel<<<dim3(384), blk, 0, stream>>>(ctx, wob, b_o, out);
}